// Round 13
// baseline (1473.681 us; speedup 1.0000x reference)
//
#include <hip/hip_runtime.h>
#include <hip/hip_bf16.h>

#define BB 8
#define SS 1024
#define CC 2
#define DD 512
#define NH 8
#define FF2 2048
#define NL 6
#define LL 1026
#define HD 64
#define MROWS 8208   // BB*LL
#define MP 8320      // padded to 65*128 (= 130*64)
#define KVPAD 1152   // keys padded to 9*128

typedef __attribute__((ext_vector_type(8))) short bf16x8;
typedef __attribute__((ext_vector_type(4))) float f32x4;

typedef __attribute__((address_space(3))) void lds_void;
typedef __attribute__((address_space(1))) void g_void;

__device__ __forceinline__ void gll16(const void* g, void* l) {
  __builtin_amdgcn_global_load_lds((const g_void*)g, (lds_void*)l, 16, 0, 0);
}

// ---------------- zero buffer (vt padding determinism) ----------------
__global__ __launch_bounds__(256) void zero_k(float4* __restrict__ p) {
  p[(size_t)blockIdx.x * 256 + threadIdx.x] = make_float4(0.f, 0.f, 0.f, 0.f);
}

// ---------------- weight fp32 -> bf16 ----------------
__global__ __launch_bounds__(256) void cvt_bf16_k(const float* __restrict__ in,
                                                  __hip_bfloat16* __restrict__ out) {
  int i = (blockIdx.x * 256 + threadIdx.x) * 4;
  float4 v = *(const float4*)&in[i];
  out[i + 0] = __float2bfloat16(v.x);
  out[i + 1] = __float2bfloat16(v.y);
  out[i + 2] = __float2bfloat16(v.z);
  out[i + 3] = __float2bfloat16(v.w);
}

// ---------------- embed + concat ----------------
__global__ __launch_bounds__(256) void embed_k(const float* __restrict__ src,
    const float* __restrict__ ctx, const int* __restrict__ times,
    const int* __restrict__ spaces, const float* __restrict__ te,
    const float* __restrict__ se, float* __restrict__ x,
    __hip_bfloat16* __restrict__ xb) {
  int row = blockIdx.x;              // 0..8207
  int b = row / LL, l = row % LL;
  int c = threadIdx.x * 2;
  float y0, y1;
  if (l < SS) {
    const float* sp = src + ((size_t)(b * SS + l)) * DD + c;
    int tt = times[b * SS + l], ssp = spaces[b * SS + l];
    y0 = sp[0] + te[tt * DD + c] + se[ssp * DD + c];
    y1 = sp[1] + te[tt * DD + c + 1] + se[ssp * DD + c + 1];
  } else {
    const float* cp = ctx + ((size_t)(b * CC + (l - SS))) * DD + c;
    y0 = cp[0]; y1 = cp[1];
  }
  size_t o = (size_t)row * DD + c;
  x[o] = y0; x[o + 1] = y1;
  xb[o] = __float2bfloat16(y0); xb[o + 1] = __float2bfloat16(y1);
}

// ---------------- GEMM 64x128 (skinny-N: Wo, W2) ----------------
// EPI: 0 = bf16 out, NO bias (bias added in ln_fuse).
template <int EPI>
__global__ __launch_bounds__(256) void gemm_bt(const __hip_bfloat16* __restrict__ A,
    const __hip_bfloat16* __restrict__ W, const float* __restrict__ bias,
    void* __restrict__ outp, int K, int N) {
  __shared__ __hip_bfloat16 As[64 * 64];    // 8 KB
  __shared__ __hip_bfloat16 Bs[128 * 64];   // 16 KB
  const int tid = threadIdx.x;
  const int lane = tid & 63, wv = tid >> 6;
  const int ny = N >> 7;
  const int nwg = gridDim.x;
  int qq = nwg >> 3, rr = nwg & 7;
  int xcd = blockIdx.x & 7, loc = blockIdx.x >> 3;
  int slot = (xcd < rr ? xcd * (qq + 1) : rr * (qq + 1) + (xcd - rr) * qq) + loc;
  const int m0 = (slot / ny) * 64, n0 = (slot % ny) * 128;
  const int r0 = lane & 15, kq = lane >> 4;
  f32x4 acc[4][2] = {};
  for (int k0 = 0; k0 < K; k0 += 64) {
    __syncthreads();
#pragma unroll
    for (int c = 0; c < 6; ++c) {
      int ch = c * 256 + tid;                 // 0..1535
      if (ch < 512) {                         // A: 512 chunks (64 rows)
        int row = ch >> 3, cp = ch & 7;
        gll16(A + (size_t)(m0 + row) * K + k0 + cp * 8, (char*)As + ch * 16);
      } else {                                // B: 1024 chunks (128 rows)
        int bi = ch - 512;
        int row = bi >> 3, cp = bi & 7;
        gll16(W + (size_t)(n0 + row) * K + k0 + cp * 8, (char*)Bs + bi * 16);
      }
    }
    __syncthreads();
#pragma unroll
    for (int kk = 0; kk < 64; kk += 32) {
      bf16x8 af[4], bfr[2];
#pragma unroll
      for (int m = 0; m < 4; ++m)
        af[m] = *(const bf16x8*)&As[(m * 16 + r0) * 64 + kk + kq * 8];
#pragma unroll
      for (int n = 0; n < 2; ++n)
        bfr[n] = *(const bf16x8*)&Bs[(wv * 32 + n * 16 + r0) * 64 + kk + kq * 8];
#pragma unroll
      for (int m = 0; m < 4; ++m)
#pragma unroll
        for (int n = 0; n < 2; ++n)
          acc[m][n] = __builtin_amdgcn_mfma_f32_16x16x32_bf16(af[m], bfr[n], acc[m][n], 0, 0, 0);
    }
  }
#pragma unroll
  for (int m = 0; m < 4; ++m) {
    int grow_base = m0 + m * 16 + kq * 4;
#pragma unroll
    for (int n = 0; n < 2; ++n) {
      int gcol = n0 + wv * 32 + n * 16 + r0;
      float bv = (EPI == 0) ? 0.f : bias[gcol];
#pragma unroll
      for (int j = 0; j < 4; ++j) {
        int grow = grow_base + j;
        float v = acc[m][n][j] + bv;
        ((__hip_bfloat16*)outp)[(size_t)grow * N + gcol] = __float2bfloat16(v);
      }
    }
  }
}

// ---------------- GEMM 128x256 (8 waves): for wide-N (QKV, FF1) ----------------
// EPI: 2 = bf16 gelu(out + bias) -> outp (stride N)
//      3 = QKV split: bias added; gcol<1024 -> qk (stride 1024);
//          gcol>=1024 -> V transposed into vtp[(b*8+h)*64+d][l]
template <int EPI>
__global__ __launch_bounds__(512) void gemm_bt2(const __hip_bfloat16* __restrict__ A,
    const __hip_bfloat16* __restrict__ W, const float* __restrict__ bias,
    void* __restrict__ outp, __hip_bfloat16* __restrict__ vtp, int K, int N) {
  __shared__ __hip_bfloat16 As[128 * 64];   // 16 KB
  __shared__ __hip_bfloat16 Bs[256 * 64];   // 32 KB
  const int tid = threadIdx.x;
  const int lane = tid & 63, wv = tid >> 6;         // 8 waves
  const int ny = N >> 8;
  const int nwg = gridDim.x;
  int qq = nwg >> 3, rr = nwg & 7;
  int xcd = blockIdx.x & 7, loc = blockIdx.x >> 3;
  int slot = (xcd < rr ? xcd * (qq + 1) : rr * (qq + 1) + (xcd - rr) * qq) + loc;
  const int m0 = (slot / ny) * 128, n0 = (slot % ny) * 256;
  const int wr = wv >> 2, wc = wv & 3;              // 2 x 4 wave grid
  const int r0 = lane & 15, kq = lane >> 4;
  f32x4 acc[4][4] = {};
  for (int k0 = 0; k0 < K; k0 += 64) {
    __syncthreads();
#pragma unroll
    for (int c = 0; c < 6; ++c) {
      int ch = c * 512 + tid;                       // 0..3071
      if (ch < 1024) {                              // A: 1024 chunks
        int row = ch >> 3, cp = ch & 7;
        gll16(A + (size_t)(m0 + row) * K + k0 + cp * 8, (char*)As + ch * 16);
      } else {                                      // B: 2048 chunks
        int bi = ch - 1024;
        int row = bi >> 3, cp = bi & 7;
        gll16(W + (size_t)(n0 + row) * K + k0 + cp * 8, (char*)Bs + bi * 16);
      }
    }
    __syncthreads();
#pragma unroll
    for (int kk = 0; kk < 64; kk += 32) {
      bf16x8 af[4], bfr[4];
#pragma unroll
      for (int m = 0; m < 4; ++m)
        af[m] = *(const bf16x8*)&As[(wr * 64 + m * 16 + r0) * 64 + kk + kq * 8];
#pragma unroll
      for (int n = 0; n < 4; ++n)
        bfr[n] = *(const bf16x8*)&Bs[(wc * 64 + n * 16 + r0) * 64 + kk + kq * 8];
#pragma unroll
      for (int m = 0; m < 4; ++m)
#pragma unroll
        for (int n = 0; n < 4; ++n)
          acc[m][n] = __builtin_amdgcn_mfma_f32_16x16x32_bf16(af[m], bfr[n], acc[m][n], 0, 0, 0);
    }
  }
#pragma unroll
  for (int m = 0; m < 4; ++m) {
    int grow_base = m0 + wr * 64 + m * 16 + kq * 4;
#pragma unroll
    for (int n = 0; n < 4; ++n) {
      int gcol = n0 + wc * 64 + n * 16 + r0;
      float bv = bias[gcol];
#pragma unroll
      for (int j = 0; j < 4; ++j) {
        int grow = grow_base + j;
        float v = acc[m][n][j] + bv;
        if (EPI == 2) {
          v = 0.5f * v * (1.f + erff(v * 0.70710678f));
          ((__hip_bfloat16*)outp)[(size_t)grow * N + gcol] = __float2bfloat16(v);
        } else {  // EPI == 3: QKV split epilogue
          if (grow < MROWS) {
            if (gcol < 1024) {
              ((__hip_bfloat16*)outp)[(size_t)grow * 1024 + gcol] = __float2bfloat16(v);
            } else {
              int b = grow / LL, l = grow - b * LL;
              int hd = gcol - 1024;
              int hh = hd >> 6, d = hd & 63;
              vtp[((size_t)((b * NH + hh) * 64 + d)) * KVPAD + l] = __float2bfloat16(v);
            }
          }
        }
      }
    }
  }
}

// ---------------- flash attention: r3 proven structure (KVBLK=128, 4 waves) ----------------
// qk: packed Q|K buffer, row stride 1024 (Q at col h*64, K at 512+h*64)
#define TK_CTX (-2000000000)
#define TQ_CTX (-1000000000)
#define TK_INV (2000000000)

__global__ __launch_bounds__(256) void attn_k(const __hip_bfloat16* __restrict__ qk,
    const __hip_bfloat16* __restrict__ vt, const int* __restrict__ times,
    __hip_bfloat16* __restrict__ aout) {
  __shared__ __hip_bfloat16 Kl[128 * 64];   // [key row][64 d], chunk^=(row&7)
  __shared__ __hip_bfloat16 Vl[64 * 128];   // [d row][128 key], chunk^=(d&7)
  __shared__ __hip_bfloat16 Pl[4][16 * 128]; // per-wave P, byte^=(q&7)<<4
  const int tid = threadIdx.x, lane = tid & 63, wv = tid >> 6;
  const int r0 = lane & 15, kq = lane >> 4;
  int i = blockIdx.x;                 // 0..1087
  int xcd = i & 7, slot = i >> 3;     // slot 0..135
  int bhl = slot / 17;
  int qb = slot - bhl * 17;
  int bh = xcd * 8 + bhl;
  int b = bh >> 3, hh = bh & 7;
  char* plbase = (char*)&Pl[wv][0];

  const int qbase = qb * 64 + wv * 16;
  int qr = qbase + r0;
  if (qr > LL - 1) qr = LL - 1;
  const __hip_bfloat16* qp = qk + (size_t)(b * LL + qr) * 1024 + hh * 64;
  bf16x8 qa0 = *(const bf16x8*)(qp + kq * 8);
  bf16x8 qa1 = *(const bf16x8*)(qp + 32 + kq * 8);
  int tq[4];
#pragma unroll
  for (int j = 0; j < 4; ++j) {
    int r = qbase + kq * 4 + j;
    tq[j] = (r < SS) ? times[b * SS + r] : TQ_CTX;
  }
  float m_run[4] = {-1e30f, -1e30f, -1e30f, -1e30f};
  float l_run[4] = {0.f, 0.f, 0.f, 0.f};
  f32x4 O[4] = {};
  const float scale = 0.125f;  // 1/sqrt(64)

  for (int kc = 0; kc < 9; ++kc) {
    __syncthreads();
#pragma unroll
    for (int c = 0; c < 4; ++c) {
      int chb = c * 256 + wv * 64;
      int ch = chb + lane;
      {
        int trow = ch >> 3, cp = ch & 7;
        int krow = kc * 128 + trow;
        if (krow > LL - 1) krow = LL - 1;
        int scp = cp ^ (trow & 7);
        gll16(qk + (size_t)(b * LL + krow) * 1024 + 512 + hh * 64 + scp * 8,
              (char*)Kl + chb * 16);
      }
      {
        int d = ch >> 4, kp = ch & 15;
        int skp = kp ^ (d & 7);
        gll16(vt + ((size_t)(bh * 64 + d)) * KVPAD + kc * 128 + skp * 8,
              (char*)Vl + chb * 16);
      }
    }
    __syncthreads();
    f32x4 s[8] = {};
#pragma unroll
    for (int n = 0; n < 8; ++n) {
      int row = n * 16 + r0;
      bf16x8 kb0 = *(const bf16x8*)&Kl[row * 64 + ((kq ^ (row & 7)) * 8)];
      bf16x8 kb1 = *(const bf16x8*)&Kl[row * 64 + (((4 + kq) ^ (row & 7)) * 8)];
      s[n] = __builtin_amdgcn_mfma_f32_16x16x32_bf16(qa0, kb0, s[n], 0, 0, 0);
      s[n] = __builtin_amdgcn_mfma_f32_16x16x32_bf16(qa1, kb1, s[n], 0, 0, 0);
    }
    int tkn[8];
#pragma unroll
    for (int n = 0; n < 8; ++n) {
      int k = kc * 128 + 16 * n + r0;
      tkn[n] = (k < SS) ? times[b * SS + k] : ((k < LL) ? TK_CTX : TK_INV);
    }
    float mch[4] = {-1e30f, -1e30f, -1e30f, -1e30f};
#pragma unroll
    for (int n = 0; n < 8; ++n)
#pragma unroll
      for (int j = 0; j < 4; ++j) {
        float sv = (tq[j] >= tkn[n]) ? s[n][j] * scale : -1e30f;
        s[n][j] = sv;
        mch[j] = fmaxf(mch[j], sv);
      }
#pragma unroll
    for (int j = 0; j < 4; ++j) {
#pragma unroll
      for (int off = 1; off < 16; off <<= 1)
        mch[j] = fmaxf(mch[j], __shfl_xor(mch[j], off, 64));
    }
    float fac[4], psum[4];
#pragma unroll
    for (int j = 0; j < 4; ++j) {
      float mn = fmaxf(m_run[j], mch[j]);
      fac[j] = __expf(m_run[j] - mn);
      m_run[j] = mn;
      psum[j] = 0.f;
    }
#pragma unroll
    for (int n = 0; n < 8; ++n)
#pragma unroll
      for (int j = 0; j < 4; ++j) {
        float p = __expf(s[n][j] - m_run[j]);
        s[n][j] = p;
        psum[j] += p;
      }
#pragma unroll
    for (int j = 0; j < 4; ++j) {
#pragma unroll
      for (int off = 1; off < 16; off <<= 1)
        psum[j] += __shfl_xor(psum[j], off, 64);
      l_run[j] = l_run[j] * fac[j] + psum[j];
    }
#pragma unroll
    for (int n = 0; n < 4; ++n)
#pragma unroll
      for (int j = 0; j < 4; ++j) O[n][j] *= fac[j];
#pragma unroll
    for (int n = 0; n < 8; ++n)
#pragma unroll
      for (int j = 0; j < 4; ++j) {
        int q = kq * 4 + j;
        int byte = ((r0 + 16 * n) * 2) ^ ((q & 7) << 4);
        *(__hip_bfloat16*)(plbase + q * 256 + byte) = __float2bfloat16(s[n][j]);
      }
#pragma unroll
    for (int c = 0; c < 4; ++c) {
      int rbyte = (c * 64 + kq * 16) ^ ((r0 & 7) << 4);
      bf16x8 pa = *(const bf16x8*)(plbase + r0 * 256 + rbyte);
#pragma unroll
      for (int n = 0; n < 4; ++n) {
        int d = n * 16 + r0;
        int chv = (c * 4 + kq) ^ (r0 & 7);
        bf16x8 vb = *(const bf16x8*)&Vl[d * 128 + chv * 8];
        O[n] = __builtin_amdgcn_mfma_f32_16x16x32_bf16(pa, vb, O[n], 0, 0, 0);
      }
    }
  }
#pragma unroll
  for (int j = 0; j < 4; ++j) {
    int orow = qbase + kq * 4 + j;
    if (orow < LL) {
      float inv = 1.f / l_run[j];
#pragma unroll
      for (int n = 0; n < 4; ++n)
        aout[(size_t)(b * LL + orow) * DD + hh * 64 + n * 16 + r0] =
            __float2bfloat16(O[n][j] * inv);
    }
  }
}

// ---------------- residual + gemm-bias + layernorm (bf16 tmp) ----------------
// fout != nullptr: also write fp32 result to fout (final output, rows l<SS)
__global__ __launch_bounds__(256) void ln_fuse_k(float* __restrict__ x,
    const __hip_bfloat16* __restrict__ tmp, const float* __restrict__ gb,
    const float* __restrict__ w, const float* __restrict__ bias,
    __hip_bfloat16* __restrict__ xb, float* __restrict__ fout) {
  const int row = blockIdx.x;
  const int tid = threadIdx.x;
  size_t o = (size_t)row * DD + tid * 2;
  float2 v = *(const float2*)&x[o];
  const __hip_bfloat16* tp = tmp + o;
  float t0 = __bfloat162float(tp[0]);
  float t1 = __bfloat162float(tp[1]);
  float a0 = v.x + gb[tid * 2] + t0, a1 = v.y + gb[tid * 2 + 1] + t1;
  float s = a0 + a1, ss = a0 * a0 + a1 * a1;
#pragma unroll
  for (int off = 1; off < 64; off <<= 1) {
    s += __shfl_xor(s, off, 64);
    ss += __shfl_xor(ss, off, 64);
  }
  __shared__ float red[8];
  const int wv = tid >> 6, lane = tid & 63;
  if (lane == 0) { red[wv] = s; red[4 + wv] = ss; }
  __syncthreads();
  s = red[0] + red[1] + red[2] + red[3];
  ss = red[4] + red[5] + red[6] + red[7];
  float mean = s * (1.f / 512.f);
  float var = ss * (1.f / 512.f) - mean * mean;
  if (var < 0.f) var = 0.f;
  float rs = rsqrtf(var + 1e-5f);
  float w0 = w[tid * 2], w1 = w[tid * 2 + 1];
  float b0 = bias[tid * 2], b1 = bias[tid * 2 + 1];
  float y0 = (a0 - mean) * rs * w0 + b0;
  float y1 = (a1 - mean) * rs * w1 + b1;
  x[o] = y0; x[o + 1] = y1;
  xb[o] = __float2bfloat16(y0); xb[o + 1] = __float2bfloat16(y1);
  if (fout != nullptr) {
    int b = row / LL, l = row - b * LL;
    if (l < SS) {
      float* fp = fout + ((size_t)(b * SS + l)) * DD + tid * 2;
      fp[0] = y0; fp[1] = y1;
    }
  }
}

extern "C" void kernel_launch(void* const* d_in, const int* in_sizes, int n_in,
                              void* d_out, int out_size, void* d_ws, size_t ws_size,
                              hipStream_t stream) {
  (void)in_sizes; (void)n_in; (void)out_size; (void)ws_size;
  const float* src    = (const float*)d_in[0];
  const float* ctx    = (const float*)d_in[1];
  const int*   times  = (const int*)d_in[2];
  const int*   spaces = (const int*)d_in[3];
  const float* te     = (const float*)d_in[5];
  const float* se     = (const float*)d_in[6];
  const float* Wqkv   = (const float*)d_in[7];
  const float* bqkv   = (const float*)d_in[8];
  const float* Wo     = (const float*)d_in[9];
  const float* bo     = (const float*)d_in[10];
  const float* ln1w   = (const float*)d_in[11];
  const float* ln1b   = (const float*)d_in[12];
  const float* W1     = (const float*)d_in[13];
  const float* b1     = (const float*)d_in[14];
  const float* W2     = (const float*)d_in[15];
  const float* b2     = (const float*)d_in[16];
  const float* ln2w   = (const float*)d_in[17];
  const float* ln2b   = (const float*)d_in[18];

  char* ws = (char*)d_ws;
  size_t off = 0;
  auto alloc = [&](size_t bytes) {
    size_t o = off;
    off += (bytes + 255) & ~(size_t)255;
    return o;
  };
  float* x            = (float*)(ws + alloc((size_t)MP * DD * 4));
  __hip_bfloat16* xb  = (__hip_bfloat16*)(ws + alloc((size_t)MP * DD * 2));
  __hip_bfloat16* qk  = (__hip_bfloat16*)(ws + alloc((size_t)MP * 1024 * 2));
  __hip_bfloat16* abf = (__hip_bfloat16*)(ws + alloc((size_t)MP * DD * 2));
  __hip_bfloat16* hbf = (__hip_bfloat16*)(ws + alloc((size_t)MP * FF2 * 2));
  __hip_bfloat16* tmp = (__hip_bfloat16*)(ws + alloc((size_t)MP * DD * 2));
  __hip_bfloat16* vt  = (__hip_bfloat16*)(ws + alloc((size_t)BB * NH * HD * KVPAD * 2));
  __hip_bfloat16* wqb = (__hip_bfloat16*)(ws + alloc((size_t)NL * 3 * DD * DD * 2));
  __hip_bfloat16* wob = (__hip_bfloat16*)(ws + alloc((size_t)NL * DD * DD * 2));
  __hip_bfloat16* w1b = (__hip_bfloat16*)(ws + alloc((size_t)NL * FF2 * DD * 2));
  __hip_bfloat16* w2b = (__hip_bfloat16*)(ws + alloc((size_t)NL * DD * FF2 * 2));

  // zero vt (padding keys l in [LL,KVPAD) must be deterministic zeros;
  // the fused QKV epilogue writes only l < LL)
  const int vtN = (int)(((size_t)BB * NH * HD * KVPAD * 2) / (256 * 16));
  zero_k<<<vtN, 256, 0, stream>>>((float4*)vt);

  // weight conversion
  cvt_bf16_k<<<(NL * 3 * DD * DD) / 1024, 256, 0, stream>>>(Wqkv, wqb);
  cvt_bf16_k<<<(NL * DD * DD) / 1024, 256, 0, stream>>>(Wo, wob);
  cvt_bf16_k<<<(NL * FF2 * DD) / 1024, 256, 0, stream>>>(W1, w1b);
  cvt_bf16_k<<<(NL * DD * FF2) / 1024, 256, 0, stream>>>(W2, w2b);

  embed_k<<<MROWS, 256, 0, stream>>>(src, ctx, times, spaces, te, se, x, xb);

  for (int i = 0; i < NL; ++i) {
    gemm_bt2<3><<<65 * 6, 512, 0, stream>>>(
        xb, wqb + (size_t)i * 3 * DD * DD, bqkv + i * 3 * DD, qk, vt, DD, 3 * DD);
    attn_k<<<1088, 256, 0, stream>>>(qk, vt, times, abf);
    gemm_bt<0><<<130 * 4, 256, 0, stream>>>(
        abf, wob + (size_t)i * DD * DD, nullptr, tmp, DD, DD);
    ln_fuse_k<<<MROWS, 256, 0, stream>>>(x, tmp, bo + i * DD,
                                         ln1w + i * DD, ln1b + i * DD, xb, nullptr);
    gemm_bt2<2><<<65 * 8, 512, 0, stream>>>(
        xb, w1b + (size_t)i * FF2 * DD, b1 + i * FF2, hbf, nullptr, DD, FF2);
    gemm_bt<0><<<130 * 4, 256, 0, stream>>>(
        hbf, w2b + (size_t)i * DD * FF2, nullptr, tmp, FF2, DD);
    ln_fuse_k<<<MROWS, 256, 0, stream>>>(x, tmp, b2 + i * DD,
                                         ln2w + i * DD, ln2b + i * DD, xb,
                                         (i == NL - 1) ? (float*)d_out : nullptr);
  }
}

// Round 14
// 1418.376 us; speedup vs baseline: 1.0390x; 1.0390x over previous
//
#include <hip/hip_runtime.h>
#include <hip/hip_bf16.h>

#define BB 8
#define SS 1024
#define CC 2
#define DD 512
#define NH 8
#define FF2 2048
#define NL 6
#define LL 1026
#define HD 64
#define MROWS 8208   // BB*LL
#define MP 8320      // padded to 65*128 (= 130*64)
#define KVPAD 1152   // keys padded to 9*128

typedef __attribute__((ext_vector_type(8))) short bf16x8;
typedef __attribute__((ext_vector_type(4))) float f32x4;

typedef __attribute__((address_space(3))) void lds_void;
typedef __attribute__((address_space(1))) void g_void;

__device__ __forceinline__ void gll16(const void* g, void* l) {
  __builtin_amdgcn_global_load_lds((const g_void*)g, (lds_void*)l, 16, 0, 0);
}

// ---------------- weight fp32 -> bf16 ----------------
__global__ __launch_bounds__(256) void cvt_bf16_k(const float* __restrict__ in,
                                                  __hip_bfloat16* __restrict__ out) {
  int i = (blockIdx.x * 256 + threadIdx.x) * 4;
  float4 v = *(const float4*)&in[i];
  out[i + 0] = __float2bfloat16(v.x);
  out[i + 1] = __float2bfloat16(v.y);
  out[i + 2] = __float2bfloat16(v.z);
  out[i + 3] = __float2bfloat16(v.w);
}

// ---------------- embed + concat ----------------
__global__ __launch_bounds__(256) void embed_k(const float* __restrict__ src,
    const float* __restrict__ ctx, const int* __restrict__ times,
    const int* __restrict__ spaces, const float* __restrict__ te,
    const float* __restrict__ se, float* __restrict__ x,
    __hip_bfloat16* __restrict__ xb) {
  int row = blockIdx.x;              // 0..8207
  int b = row / LL, l = row % LL;
  int c = threadIdx.x * 2;
  float y0, y1;
  if (l < SS) {
    const float* sp = src + ((size_t)(b * SS + l)) * DD + c;
    int tt = times[b * SS + l], ssp = spaces[b * SS + l];
    y0 = sp[0] + te[tt * DD + c] + se[ssp * DD + c];
    y1 = sp[1] + te[tt * DD + c + 1] + se[ssp * DD + c + 1];
  } else {
    const float* cp = ctx + ((size_t)(b * CC + (l - SS))) * DD + c;
    y0 = cp[0]; y1 = cp[1];
  }
  size_t o = (size_t)row * DD + c;
  x[o] = y0; x[o + 1] = y1;
  xb[o] = __float2bfloat16(y0); xb[o + 1] = __float2bfloat16(y1);
}

// ---------------- GEMM 64x128 (skinny-N: Wo, W2) ----------------
// EPI: 0 = bf16 out, NO bias (bias added in ln_fuse).
template <int EPI>
__global__ __launch_bounds__(256) void gemm_bt(const __hip_bfloat16* __restrict__ A,
    const __hip_bfloat16* __restrict__ W, const float* __restrict__ bias,
    void* __restrict__ outp, int K, int N) {
  __shared__ __hip_bfloat16 As[64 * 64];    // 8 KB
  __shared__ __hip_bfloat16 Bs[128 * 64];   // 16 KB
  const int tid = threadIdx.x;
  const int lane = tid & 63, wv = tid >> 6;
  const int ny = N >> 7;
  const int nwg = gridDim.x;
  int qq = nwg >> 3, rr = nwg & 7;
  int xcd = blockIdx.x & 7, loc = blockIdx.x >> 3;
  int slot = (xcd < rr ? xcd * (qq + 1) : rr * (qq + 1) + (xcd - rr) * qq) + loc;
  const int m0 = (slot / ny) * 64, n0 = (slot % ny) * 128;
  const int r0 = lane & 15, kq = lane >> 4;
  f32x4 acc[4][2] = {};
  for (int k0 = 0; k0 < K; k0 += 64) {
    __syncthreads();
#pragma unroll
    for (int c = 0; c < 6; ++c) {
      int ch = c * 256 + tid;                 // 0..1535
      if (ch < 512) {                         // A: 512 chunks (64 rows)
        int row = ch >> 3, cp = ch & 7;
        gll16(A + (size_t)(m0 + row) * K + k0 + cp * 8, (char*)As + ch * 16);
      } else {                                // B: 1024 chunks (128 rows)
        int bi = ch - 512;
        int row = bi >> 3, cp = bi & 7;
        gll16(W + (size_t)(n0 + row) * K + k0 + cp * 8, (char*)Bs + bi * 16);
      }
    }
    __syncthreads();
#pragma unroll
    for (int kk = 0; kk < 64; kk += 32) {
      bf16x8 af[4], bfr[2];
#pragma unroll
      for (int m = 0; m < 4; ++m)
        af[m] = *(const bf16x8*)&As[(m * 16 + r0) * 64 + kk + kq * 8];
#pragma unroll
      for (int n = 0; n < 2; ++n)
        bfr[n] = *(const bf16x8*)&Bs[(wv * 32 + n * 16 + r0) * 64 + kk + kq * 8];
#pragma unroll
      for (int m = 0; m < 4; ++m)
#pragma unroll
        for (int n = 0; n < 2; ++n)
          acc[m][n] = __builtin_amdgcn_mfma_f32_16x16x32_bf16(af[m], bfr[n], acc[m][n], 0, 0, 0);
    }
  }
#pragma unroll
  for (int m = 0; m < 4; ++m) {
    int grow_base = m0 + m * 16 + kq * 4;
#pragma unroll
    for (int n = 0; n < 2; ++n) {
      int gcol = n0 + wv * 32 + n * 16 + r0;
      float bv = (EPI == 0) ? 0.f : bias[gcol];
#pragma unroll
      for (int j = 0; j < 4; ++j) {
        int grow = grow_base + j;
        float v = acc[m][n][j] + bv;
        ((__hip_bfloat16*)outp)[(size_t)grow * N + gcol] = __float2bfloat16(v);
      }
    }
  }
}

// ---------------- GEMM 128x256 (8 waves): for wide-N (QKV, FF1) ----------------
template <int EPI>
__global__ __launch_bounds__(512) void gemm_bt2(const __hip_bfloat16* __restrict__ A,
    const __hip_bfloat16* __restrict__ W, const float* __restrict__ bias,
    void* __restrict__ outp, int K, int N) {
  __shared__ __hip_bfloat16 As[128 * 64];   // 16 KB
  __shared__ __hip_bfloat16 Bs[256 * 64];   // 32 KB
  const int tid = threadIdx.x;
  const int lane = tid & 63, wv = tid >> 6;         // 8 waves
  const int ny = N >> 8;
  const int nwg = gridDim.x;
  int qq = nwg >> 3, rr = nwg & 7;
  int xcd = blockIdx.x & 7, loc = blockIdx.x >> 3;
  int slot = (xcd < rr ? xcd * (qq + 1) : rr * (qq + 1) + (xcd - rr) * qq) + loc;
  const int m0 = (slot / ny) * 128, n0 = (slot % ny) * 256;
  const int wr = wv >> 2, wc = wv & 3;              // 2 x 4 wave grid
  const int r0 = lane & 15, kq = lane >> 4;
  f32x4 acc[4][4] = {};
  for (int k0 = 0; k0 < K; k0 += 64) {
    __syncthreads();
#pragma unroll
    for (int c = 0; c < 6; ++c) {
      int ch = c * 512 + tid;                       // 0..3071
      if (ch < 1024) {                              // A: 1024 chunks
        int row = ch >> 3, cp = ch & 7;
        gll16(A + (size_t)(m0 + row) * K + k0 + cp * 8, (char*)As + ch * 16);
      } else {                                      // B: 2048 chunks
        int bi = ch - 1024;
        int row = bi >> 3, cp = bi & 7;
        gll16(W + (size_t)(n0 + row) * K + k0 + cp * 8, (char*)Bs + bi * 16);
      }
    }
    __syncthreads();
#pragma unroll
    for (int kk = 0; kk < 64; kk += 32) {
      bf16x8 af[4], bfr[4];
#pragma unroll
      for (int m = 0; m < 4; ++m)
        af[m] = *(const bf16x8*)&As[(wr * 64 + m * 16 + r0) * 64 + kk + kq * 8];
#pragma unroll
      for (int n = 0; n < 4; ++n)
        bfr[n] = *(const bf16x8*)&Bs[(wc * 64 + n * 16 + r0) * 64 + kk + kq * 8];
#pragma unroll
      for (int m = 0; m < 4; ++m)
#pragma unroll
        for (int n = 0; n < 4; ++n)
          acc[m][n] = __builtin_amdgcn_mfma_f32_16x16x32_bf16(af[m], bfr[n], acc[m][n], 0, 0, 0);
    }
  }
#pragma unroll
  for (int m = 0; m < 4; ++m) {
    int grow_base = m0 + wr * 64 + m * 16 + kq * 4;
#pragma unroll
    for (int n = 0; n < 4; ++n) {
      int gcol = n0 + wc * 64 + n * 16 + r0;
      float bv = bias[gcol];
#pragma unroll
      for (int j = 0; j < 4; ++j) {
        int grow = grow_base + j;
        float v = acc[m][n][j] + bv;
        if (EPI == 2) v = 0.5f * v * (1.f + erff(v * 0.70710678f));
        ((__hip_bfloat16*)outp)[(size_t)grow * N + gcol] = __float2bfloat16(v);
      }
    }
  }
}

// ---------------- V transpose: vt[bh][d][key] ----------------
__global__ __launch_bounds__(256) void vtrans_k(const __hip_bfloat16* __restrict__ qkv,
                                                __hip_bfloat16* __restrict__ vt) {
  __shared__ __hip_bfloat16 tile[64][72];
  int bh = blockIdx.y;
  int b = bh >> 3, hh = bh & 7;
  int l0 = blockIdx.x * 64;
  int t = threadIdx.x;
  int lr = t >> 2, part = t & 3;
  int l = l0 + lr;
  if (l < LL) {
    const __hip_bfloat16* p = qkv + (size_t)(b * LL + l) * 1536 + 1024 + hh * 64 + part * 16;
    *(uint4*)&tile[lr][part * 16] = *(const uint4*)p;
    *(uint4*)&tile[lr][part * 16 + 8] = *(const uint4*)(p + 8);
  } else {
    uint4 z = make_uint4(0, 0, 0, 0);
    *(uint4*)&tile[lr][part * 16] = z;
    *(uint4*)&tile[lr][part * 16 + 8] = z;
  }
  __syncthreads();
  int d = t >> 2, kp = t & 3;
  __hip_bfloat16 vals[16];
#pragma unroll
  for (int i = 0; i < 16; ++i) vals[i] = tile[kp * 16 + i][d];
  __hip_bfloat16* o = vt + ((size_t)(bh * 64 + d)) * KVPAD + l0 + kp * 16;
  *(uint4*)o = *(uint4*)&vals[0];
  *(uint4*)(o + 8) = *(uint4*)&vals[8];
}

// ---------------- flash attention: r3 proven structure (KVBLK=128, 4 waves) ----------------
#define TK_CTX (-2000000000)
#define TQ_CTX (-1000000000)
#define TK_INV (2000000000)

__global__ __launch_bounds__(256) void attn_k(const __hip_bfloat16* __restrict__ qkv,
    const __hip_bfloat16* __restrict__ vt, const int* __restrict__ times,
    __hip_bfloat16* __restrict__ aout) {
  __shared__ __hip_bfloat16 Kl[128 * 64];   // [key row][64 d], chunk^=(row&7)
  __shared__ __hip_bfloat16 Vl[64 * 128];   // [d row][128 key], chunk^=(d&7)
  __shared__ __hip_bfloat16 Pl[4][16 * 128]; // per-wave P, byte^=(q&7)<<4
  const int tid = threadIdx.x, lane = tid & 63, wv = tid >> 6;
  const int r0 = lane & 15, kq = lane >> 4;
  int i = blockIdx.x;                 // 0..1087
  int xcd = i & 7, slot = i >> 3;     // slot 0..135
  int bhl = slot / 17;
  int qb = slot - bhl * 17;
  int bh = xcd * 8 + bhl;
  int b = bh >> 3, hh = bh & 7;
  char* plbase = (char*)&Pl[wv][0];

  const int qbase = qb * 64 + wv * 16;
  int qr = qbase + r0;
  if (qr > LL - 1) qr = LL - 1;
  const __hip_bfloat16* qp = qkv + (size_t)(b * LL + qr) * 1536 + hh * 64;
  bf16x8 qa0 = *(const bf16x8*)(qp + kq * 8);
  bf16x8 qa1 = *(const bf16x8*)(qp + 32 + kq * 8);
  int tq[4];
#pragma unroll
  for (int j = 0; j < 4; ++j) {
    int r = qbase + kq * 4 + j;
    tq[j] = (r < SS) ? times[b * SS + r] : TQ_CTX;
  }
  float m_run[4] = {-1e30f, -1e30f, -1e30f, -1e30f};
  float l_run[4] = {0.f, 0.f, 0.f, 0.f};
  f32x4 O[4] = {};
  const float scale = 0.125f;  // 1/sqrt(64)

  for (int kc = 0; kc < 9; ++kc) {
    __syncthreads();
#pragma unroll
    for (int c = 0; c < 4; ++c) {
      int chb = c * 256 + wv * 64;
      int ch = chb + lane;
      {
        int trow = ch >> 3, cp = ch & 7;
        int krow = kc * 128 + trow;
        if (krow > LL - 1) krow = LL - 1;
        int scp = cp ^ (trow & 7);
        gll16(qkv + (size_t)(b * LL + krow) * 1536 + 512 + hh * 64 + scp * 8,
              (char*)Kl + chb * 16);
      }
      {
        int d = ch >> 4, kp = ch & 15;
        int skp = kp ^ (d & 7);
        gll16(vt + ((size_t)(bh * 64 + d)) * KVPAD + kc * 128 + skp * 8,
              (char*)Vl + chb * 16);
      }
    }
    __syncthreads();
    f32x4 s[8] = {};
#pragma unroll
    for (int n = 0; n < 8; ++n) {
      int row = n * 16 + r0;
      bf16x8 kb0 = *(const bf16x8*)&Kl[row * 64 + ((kq ^ (row & 7)) * 8)];
      bf16x8 kb1 = *(const bf16x8*)&Kl[row * 64 + (((4 + kq) ^ (row & 7)) * 8)];
      s[n] = __builtin_amdgcn_mfma_f32_16x16x32_bf16(qa0, kb0, s[n], 0, 0, 0);
      s[n] = __builtin_amdgcn_mfma_f32_16x16x32_bf16(qa1, kb1, s[n], 0, 0, 0);
    }
    int tkn[8];
#pragma unroll
    for (int n = 0; n < 8; ++n) {
      int k = kc * 128 + 16 * n + r0;
      tkn[n] = (k < SS) ? times[b * SS + k] : ((k < LL) ? TK_CTX : TK_INV);
    }
    float mch[4] = {-1e30f, -1e30f, -1e30f, -1e30f};
#pragma unroll
    for (int n = 0; n < 8; ++n)
#pragma unroll
      for (int j = 0; j < 4; ++j) {
        float sv = (tq[j] >= tkn[n]) ? s[n][j] * scale : -1e30f;
        s[n][j] = sv;
        mch[j] = fmaxf(mch[j], sv);
      }
#pragma unroll
    for (int j = 0; j < 4; ++j) {
#pragma unroll
      for (int off = 1; off < 16; off <<= 1)
        mch[j] = fmaxf(mch[j], __shfl_xor(mch[j], off, 64));
    }
    float fac[4], psum[4];
#pragma unroll
    for (int j = 0; j < 4; ++j) {
      float mn = fmaxf(m_run[j], mch[j]);
      fac[j] = __expf(m_run[j] - mn);
      m_run[j] = mn;
      psum[j] = 0.f;
    }
#pragma unroll
    for (int n = 0; n < 8; ++n)
#pragma unroll
      for (int j = 0; j < 4; ++j) {
        float p = __expf(s[n][j] - m_run[j]);
        s[n][j] = p;
        psum[j] += p;
      }
#pragma unroll
    for (int j = 0; j < 4; ++j) {
#pragma unroll
      for (int off = 1; off < 16; off <<= 1)
        psum[j] += __shfl_xor(psum[j], off, 64);
      l_run[j] = l_run[j] * fac[j] + psum[j];
    }
#pragma unroll
    for (int n = 0; n < 4; ++n)
#pragma unroll
      for (int j = 0; j < 4; ++j) O[n][j] *= fac[j];
#pragma unroll
    for (int n = 0; n < 8; ++n)
#pragma unroll
      for (int j = 0; j < 4; ++j) {
        int q = kq * 4 + j;
        int byte = ((r0 + 16 * n) * 2) ^ ((q & 7) << 4);
        *(__hip_bfloat16*)(plbase + q * 256 + byte) = __float2bfloat16(s[n][j]);
      }
#pragma unroll
    for (int c = 0; c < 4; ++c) {
      int rbyte = (c * 64 + kq * 16) ^ ((r0 & 7) << 4);
      bf16x8 pa = *(const bf16x8*)(plbase + r0 * 256 + rbyte);
#pragma unroll
      for (int n = 0; n < 4; ++n) {
        int d = n * 16 + r0;
        int chv = (c * 4 + kq) ^ (r0 & 7);
        bf16x8 vb = *(const bf16x8*)&Vl[d * 128 + chv * 8];
        O[n] = __builtin_amdgcn_mfma_f32_16x16x32_bf16(pa, vb, O[n], 0, 0, 0);
      }
    }
  }
#pragma unroll
  for (int j = 0; j < 4; ++j) {
    int orow = qbase + kq * 4 + j;
    if (orow < LL) {
      float inv = 1.f / l_run[j];
#pragma unroll
      for (int n = 0; n < 4; ++n)
        aout[(size_t)(b * LL + orow) * DD + hh * 64 + n * 16 + r0] =
            __float2bfloat16(O[n][j] * inv);
    }
  }
}

// ---------------- residual + gemm-bias + layernorm (bf16 tmp) ----------------
// fout != nullptr: also write fp32 result to fout (final output, rows l<SS)
__global__ __launch_bounds__(256) void ln_fuse_k(float* __restrict__ x,
    const __hip_bfloat16* __restrict__ tmp, const float* __restrict__ gb,
    const float* __restrict__ w, const float* __restrict__ bias,
    __hip_bfloat16* __restrict__ xb, float* __restrict__ fout) {
  const int row = blockIdx.x;
  const int tid = threadIdx.x;
  size_t o = (size_t)row * DD + tid * 2;
  float2 v = *(const float2*)&x[o];
  const __hip_bfloat16* tp = tmp + o;
  float t0 = __bfloat162float(tp[0]);
  float t1 = __bfloat162float(tp[1]);
  float a0 = v.x + gb[tid * 2] + t0, a1 = v.y + gb[tid * 2 + 1] + t1;
  float s = a0 + a1, ss = a0 * a0 + a1 * a1;
#pragma unroll
  for (int off = 1; off < 64; off <<= 1) {
    s += __shfl_xor(s, off, 64);
    ss += __shfl_xor(ss, off, 64);
  }
  __shared__ float red[8];
  const int wv = tid >> 6, lane = tid & 63;
  if (lane == 0) { red[wv] = s; red[4 + wv] = ss; }
  __syncthreads();
  s = red[0] + red[1] + red[2] + red[3];
  ss = red[4] + red[5] + red[6] + red[7];
  float mean = s * (1.f / 512.f);
  float var = ss * (1.f / 512.f) - mean * mean;
  if (var < 0.f) var = 0.f;
  float rs = rsqrtf(var + 1e-5f);
  float w0 = w[tid * 2], w1 = w[tid * 2 + 1];
  float b0 = bias[tid * 2], b1 = bias[tid * 2 + 1];
  float y0 = (a0 - mean) * rs * w0 + b0;
  float y1 = (a1 - mean) * rs * w1 + b1;
  x[o] = y0; x[o + 1] = y1;
  xb[o] = __float2bfloat16(y0); xb[o + 1] = __float2bfloat16(y1);
  if (fout != nullptr) {
    int b = row / LL, l = row - b * LL;
    if (l < SS) {
      float* fp = fout + ((size_t)(b * SS + l)) * DD + tid * 2;
      fp[0] = y0; fp[1] = y1;
    }
  }
}

extern "C" void kernel_launch(void* const* d_in, const int* in_sizes, int n_in,
                              void* d_out, int out_size, void* d_ws, size_t ws_size,
                              hipStream_t stream) {
  (void)in_sizes; (void)n_in; (void)out_size; (void)ws_size;
  const float* src    = (const float*)d_in[0];
  const float* ctx    = (const float*)d_in[1];
  const int*   times  = (const int*)d_in[2];
  const int*   spaces = (const int*)d_in[3];
  const float* te     = (const float*)d_in[5];
  const float* se     = (const float*)d_in[6];
  const float* Wqkv   = (const float*)d_in[7];
  const float* bqkv   = (const float*)d_in[8];
  const float* Wo     = (const float*)d_in[9];
  const float* bo     = (const float*)d_in[10];
  const float* ln1w   = (const float*)d_in[11];
  const float* ln1b   = (const float*)d_in[12];
  const float* W1     = (const float*)d_in[13];
  const float* b1     = (const float*)d_in[14];
  const float* W2     = (const float*)d_in[15];
  const float* b2     = (const float*)d_in[16];
  const float* ln2w   = (const float*)d_in[17];
  const float* ln2b   = (const float*)d_in[18];

  char* ws = (char*)d_ws;
  size_t off = 0;
  auto alloc = [&](size_t bytes) {
    size_t o = off;
    off += (bytes + 255) & ~(size_t)255;
    return o;
  };
  float* x            = (float*)(ws + alloc((size_t)MP * DD * 4));
  __hip_bfloat16* xb  = (__hip_bfloat16*)(ws + alloc((size_t)MP * DD * 2));
  __hip_bfloat16* qkv = (__hip_bfloat16*)(ws + alloc((size_t)MP * 3 * DD * 2));
  __hip_bfloat16* abf = (__hip_bfloat16*)(ws + alloc((size_t)MP * DD * 2));
  __hip_bfloat16* hbf = (__hip_bfloat16*)(ws + alloc((size_t)MP * FF2 * 2));
  __hip_bfloat16* tmp = (__hip_bfloat16*)(ws + alloc((size_t)MP * DD * 2));
  __hip_bfloat16* vt  = (__hip_bfloat16*)(ws + alloc((size_t)BB * NH * HD * KVPAD * 2));
  __hip_bfloat16* wqb = (__hip_bfloat16*)(ws + alloc((size_t)NL * 3 * DD * DD * 2));
  __hip_bfloat16* wob = (__hip_bfloat16*)(ws + alloc((size_t)NL * DD * DD * 2));
  __hip_bfloat16* w1b = (__hip_bfloat16*)(ws + alloc((size_t)NL * FF2 * DD * 2));
  __hip_bfloat16* w2b = (__hip_bfloat16*)(ws + alloc((size_t)NL * DD * FF2 * 2));

  // weight conversion
  cvt_bf16_k<<<(NL * 3 * DD * DD) / 1024, 256, 0, stream>>>(Wqkv, wqb);
  cvt_bf16_k<<<(NL * DD * DD) / 1024, 256, 0, stream>>>(Wo, wob);
  cvt_bf16_k<<<(NL * FF2 * DD) / 1024, 256, 0, stream>>>(W1, w1b);
  cvt_bf16_k<<<(NL * DD * FF2) / 1024, 256, 0, stream>>>(W2, w2b);

  embed_k<<<MROWS, 256, 0, stream>>>(src, ctx, times, spaces, te, se, x, xb);

  for (int i = 0; i < NL; ++i) {
    gemm_bt2<1><<<65 * 6, 512, 0, stream>>>(
        xb, wqb + (size_t)i * 3 * DD * DD, bqkv + i * 3 * DD, qkv, DD, 3 * DD);
    vtrans_k<<<dim3(17, BB * NH), 256, 0, stream>>>(qkv, vt);
    attn_k<<<1088, 256, 0, stream>>>(qkv, vt, times, abf);
    gemm_bt<0><<<130 * 4, 256, 0, stream>>>(
        abf, wob + (size_t)i * DD * DD, nullptr, tmp, DD, DD);
    ln_fuse_k<<<MROWS, 256, 0, stream>>>(x, tmp, bo + i * DD,
                                         ln1w + i * DD, ln1b + i * DD, xb, nullptr);
    gemm_bt2<2><<<65 * 8, 512, 0, stream>>>(
        xb, w1b + (size_t)i * FF2 * DD, b1 + i * FF2, hbf, DD, FF2);
    gemm_bt<0><<<130 * 4, 256, 0, stream>>>(
        hbf, w2b + (size_t)i * DD * FF2, nullptr, tmp, FF2, DD);
    ln_fuse_k<<<MROWS, 256, 0, stream>>>(x, tmp, b2 + i * DD,
                                         ln2w + i * DD, ln2b + i * DD, xb,
                                         (i == NL - 1) ? (float*)d_out : nullptr);
  }
}

// Round 15
// 1326.126 us; speedup vs baseline: 1.1113x; 1.0696x over previous
//
#include <hip/hip_runtime.h>
#include <hip/hip_bf16.h>

#define BB 8
#define SS 1024
#define CC 2
#define DD 512
#define NH 8
#define FF2 2048
#define NL 6
#define LL 1026
#define HD 64
#define MROWS 8208   // BB*LL
#define MP 8320      // padded to 65*128 (= 130*64)
#define KVPAD 1152   // keys padded to 9*128

typedef __attribute__((ext_vector_type(8))) short bf16x8;
typedef __attribute__((ext_vector_type(4))) float f32x4;

typedef __attribute__((address_space(3))) void lds_void;
typedef __attribute__((address_space(1))) void g_void;

__device__ __forceinline__ void gll16(const void* g, void* l) {
  __builtin_amdgcn_global_load_lds((const g_void*)g, (lds_void*)l, 16, 0, 0);
}

// ---------------- weight fp32 -> bf16 ----------------
__global__ __launch_bounds__(256) void cvt_bf16_k(const float* __restrict__ in,
                                                  __hip_bfloat16* __restrict__ out) {
  int i = (blockIdx.x * 256 + threadIdx.x) * 4;
  float4 v = *(const float4*)&in[i];
  out[i + 0] = __float2bfloat16(v.x);
  out[i + 1] = __float2bfloat16(v.y);
  out[i + 2] = __float2bfloat16(v.z);
  out[i + 3] = __float2bfloat16(v.w);
}

// ---------------- embed + concat ----------------
__global__ __launch_bounds__(256) void embed_k(const float* __restrict__ src,
    const float* __restrict__ ctx, const int* __restrict__ times,
    const int* __restrict__ spaces, const float* __restrict__ te,
    const float* __restrict__ se, float* __restrict__ x,
    __hip_bfloat16* __restrict__ xb) {
  int row = blockIdx.x;              // 0..8207
  int b = row / LL, l = row % LL;
  int c = threadIdx.x * 2;
  float y0, y1;
  if (l < SS) {
    const float* sp = src + ((size_t)(b * SS + l)) * DD + c;
    int tt = times[b * SS + l], ssp = spaces[b * SS + l];
    y0 = sp[0] + te[tt * DD + c] + se[ssp * DD + c];
    y1 = sp[1] + te[tt * DD + c + 1] + se[ssp * DD + c + 1];
  } else {
    const float* cp = ctx + ((size_t)(b * CC + (l - SS))) * DD + c;
    y0 = cp[0]; y1 = cp[1];
  }
  size_t o = (size_t)row * DD + c;
  x[o] = y0; x[o + 1] = y1;
  xb[o] = __float2bfloat16(y0); xb[o + 1] = __float2bfloat16(y1);
}

// ---------------- GEMM 64x128 (skinny-N: Wo, W2), BK=32 counted-vmcnt dbuf ----
// EPI: 0 = bf16 out, NO bias (bias added in ln_fuse).
// T4 pattern: STAGE(t+1); vmcnt(3) [waits own tile-t loads, keeps t+1 in
// flight]; barrier; COMPUTE(t); barrier [protects buffer reuse].
template <int EPI>
__global__ __launch_bounds__(256) void gemm_bt(const __hip_bfloat16* __restrict__ A,
    const __hip_bfloat16* __restrict__ W, const float* __restrict__ bias,
    void* __restrict__ outp, int K, int N) {
  __shared__ __hip_bfloat16 As[2][64 * 32];    // 4 KB each
  __shared__ __hip_bfloat16 Bs[2][128 * 32];   // 8 KB each (24 KB total)
  const int tid = threadIdx.x;
  const int lane = tid & 63, wv = tid >> 6;
  const int ny = N >> 7;
  const int nwg = gridDim.x;
  int qq = nwg >> 3, rr = nwg & 7;
  int xcd = blockIdx.x & 7, loc = blockIdx.x >> 3;
  int slot = (xcd < rr ? xcd * (qq + 1) : rr * (qq + 1) + (xcd - rr) * qq) + loc;
  const int m0 = (slot / ny) * 64, n0 = (slot % ny) * 128;
  const int r0 = lane & 15, kq = lane >> 4;
  f32x4 acc[4][2] = {};

  auto STAGE = [&](int nb, int t) {
    int k0 = t * 32;
#pragma unroll
    for (int c = 0; c < 3; ++c) {
      int ch = c * 256 + tid;                 // 0..767
      if (ch < 256) {                         // A: 256 chunks (64 rows x 4)
        int row = ch >> 2, cp = ch & 3;
        gll16(A + (size_t)(m0 + row) * K + k0 + cp * 8, (char*)&As[nb][0] + ch * 16);
      } else {                                // B: 512 chunks (128 rows x 4)
        int bi = ch - 256;
        int row = bi >> 2, cp = bi & 3;
        gll16(W + (size_t)(n0 + row) * K + k0 + cp * 8, (char*)&Bs[nb][0] + bi * 16);
      }
    }
  };
  auto COMPUTE = [&](int nb) {
    bf16x8 af[4], bfr[2];
#pragma unroll
    for (int m = 0; m < 4; ++m)
      af[m] = *(const bf16x8*)&As[nb][(m * 16 + r0) * 32 + kq * 8];
#pragma unroll
    for (int n = 0; n < 2; ++n)
      bfr[n] = *(const bf16x8*)&Bs[nb][(wv * 32 + n * 16 + r0) * 32 + kq * 8];
#pragma unroll
    for (int m = 0; m < 4; ++m)
#pragma unroll
      for (int n = 0; n < 2; ++n)
        acc[m][n] = __builtin_amdgcn_mfma_f32_16x16x32_bf16(af[m], bfr[n], acc[m][n], 0, 0, 0);
  };

  const int nt = K >> 5;
  STAGE(0, 0);
  asm volatile("s_waitcnt vmcnt(0)" ::: "memory");
  __builtin_amdgcn_s_barrier();
  for (int t = 0; t < nt - 1; ++t) {
    STAGE((t + 1) & 1, t + 1);
    asm volatile("s_waitcnt vmcnt(3)" ::: "memory");
    __builtin_amdgcn_s_barrier();
    __builtin_amdgcn_sched_barrier(0);
    COMPUTE(t & 1);
    __builtin_amdgcn_s_barrier();
  }
  asm volatile("s_waitcnt vmcnt(0)" ::: "memory");
  __builtin_amdgcn_s_barrier();
  __builtin_amdgcn_sched_barrier(0);
  COMPUTE((nt - 1) & 1);

#pragma unroll
  for (int m = 0; m < 4; ++m) {
    int grow_base = m0 + m * 16 + kq * 4;
#pragma unroll
    for (int n = 0; n < 2; ++n) {
      int gcol = n0 + wv * 32 + n * 16 + r0;
      float bv = (EPI == 0) ? 0.f : bias[gcol];
#pragma unroll
      for (int j = 0; j < 4; ++j) {
        int grow = grow_base + j;
        float v = acc[m][n][j] + bv;
        ((__hip_bfloat16*)outp)[(size_t)grow * N + gcol] = __float2bfloat16(v);
      }
    }
  }
}

// ---------------- GEMM 128x256 (8 waves, wide-N), BK=32 counted-vmcnt dbuf ----
template <int EPI>
__global__ __launch_bounds__(512) void gemm_bt2(const __hip_bfloat16* __restrict__ A,
    const __hip_bfloat16* __restrict__ W, const float* __restrict__ bias,
    void* __restrict__ outp, int K, int N) {
  __shared__ __hip_bfloat16 As[2][128 * 32];   // 8 KB each
  __shared__ __hip_bfloat16 Bs[2][256 * 32];   // 16 KB each (48 KB total)
  const int tid = threadIdx.x;
  const int lane = tid & 63, wv = tid >> 6;         // 8 waves
  const int ny = N >> 8;
  const int nwg = gridDim.x;
  int qq = nwg >> 3, rr = nwg & 7;
  int xcd = blockIdx.x & 7, loc = blockIdx.x >> 3;
  int slot = (xcd < rr ? xcd * (qq + 1) : rr * (qq + 1) + (xcd - rr) * qq) + loc;
  const int m0 = (slot / ny) * 128, n0 = (slot % ny) * 256;
  const int wr = wv >> 2, wc = wv & 3;              // 2 x 4 wave grid
  const int r0 = lane & 15, kq = lane >> 4;
  f32x4 acc[4][4] = {};

  auto STAGE = [&](int nb, int t) {
    int k0 = t * 32;
#pragma unroll
    for (int c = 0; c < 3; ++c) {
      int ch = c * 512 + tid;                       // 0..1535
      if (ch < 512) {                               // A: 512 chunks (128 rows x 4)
        int row = ch >> 2, cp = ch & 3;
        gll16(A + (size_t)(m0 + row) * K + k0 + cp * 8, (char*)&As[nb][0] + ch * 16);
      } else {                                      // B: 1024 chunks (256 rows x 4)
        int bi = ch - 512;
        int row = bi >> 2, cp = bi & 3;
        gll16(W + (size_t)(n0 + row) * K + k0 + cp * 8, (char*)&Bs[nb][0] + bi * 16);
      }
    }
  };
  auto COMPUTE = [&](int nb) {
    bf16x8 af[4], bfr[4];
#pragma unroll
    for (int m = 0; m < 4; ++m)
      af[m] = *(const bf16x8*)&As[nb][(wr * 64 + m * 16 + r0) * 32 + kq * 8];
#pragma unroll
    for (int n = 0; n < 4; ++n)
      bfr[n] = *(const bf16x8*)&Bs[nb][(wc * 64 + n * 16 + r0) * 32 + kq * 8];
#pragma unroll
    for (int m = 0; m < 4; ++m)
#pragma unroll
      for (int n = 0; n < 4; ++n)
        acc[m][n] = __builtin_amdgcn_mfma_f32_16x16x32_bf16(af[m], bfr[n], acc[m][n], 0, 0, 0);
  };

  const int nt = K >> 5;
  STAGE(0, 0);
  asm volatile("s_waitcnt vmcnt(0)" ::: "memory");
  __builtin_amdgcn_s_barrier();
  for (int t = 0; t < nt - 1; ++t) {
    STAGE((t + 1) & 1, t + 1);
    asm volatile("s_waitcnt vmcnt(3)" ::: "memory");
    __builtin_amdgcn_s_barrier();
    __builtin_amdgcn_sched_barrier(0);
    COMPUTE(t & 1);
    __builtin_amdgcn_s_barrier();
  }
  asm volatile("s_waitcnt vmcnt(0)" ::: "memory");
  __builtin_amdgcn_s_barrier();
  __builtin_amdgcn_sched_barrier(0);
  COMPUTE((nt - 1) & 1);

#pragma unroll
  for (int m = 0; m < 4; ++m) {
    int grow_base = m0 + wr * 64 + m * 16 + kq * 4;
#pragma unroll
    for (int n = 0; n < 4; ++n) {
      int gcol = n0 + wc * 64 + n * 16 + r0;
      float bv = bias[gcol];
#pragma unroll
      for (int j = 0; j < 4; ++j) {
        int grow = grow_base + j;
        float v = acc[m][n][j] + bv;
        if (EPI == 2) v = 0.5f * v * (1.f + erff(v * 0.70710678f));
        ((__hip_bfloat16*)outp)[(size_t)grow * N + gcol] = __float2bfloat16(v);
      }
    }
  }
}

// ---------------- V transpose: vt[bh][d][key] ----------------
__global__ __launch_bounds__(256) void vtrans_k(const __hip_bfloat16* __restrict__ qkv,
                                                __hip_bfloat16* __restrict__ vt) {
  __shared__ __hip_bfloat16 tile[64][72];
  int bh = blockIdx.y;
  int b = bh >> 3, hh = bh & 7;
  int l0 = blockIdx.x * 64;
  int t = threadIdx.x;
  int lr = t >> 2, part = t & 3;
  int l = l0 + lr;
  if (l < LL) {
    const __hip_bfloat16* p = qkv + (size_t)(b * LL + l) * 1536 + 1024 + hh * 64 + part * 16;
    *(uint4*)&tile[lr][part * 16] = *(const uint4*)p;
    *(uint4*)&tile[lr][part * 16 + 8] = *(const uint4*)(p + 8);
  } else {
    uint4 z = make_uint4(0, 0, 0, 0);
    *(uint4*)&tile[lr][part * 16] = z;
    *(uint4*)&tile[lr][part * 16 + 8] = z;
  }
  __syncthreads();
  int d = t >> 2, kp = t & 3;
  __hip_bfloat16 vals[16];
#pragma unroll
  for (int i = 0; i < 16; ++i) vals[i] = tile[kp * 16 + i][d];
  __hip_bfloat16* o = vt + ((size_t)(bh * 64 + d)) * KVPAD + l0 + kp * 16;
  *(uint4*)o = *(uint4*)&vals[0];
  *(uint4*)(o + 8) = *(uint4*)&vals[8];
}

// ---------------- flash attention: r3 proven structure (KVBLK=128, 4 waves) ----------------
#define TK_CTX (-2000000000)
#define TQ_CTX (-1000000000)
#define TK_INV (2000000000)

__global__ __launch_bounds__(256) void attn_k(const __hip_bfloat16* __restrict__ qkv,
    const __hip_bfloat16* __restrict__ vt, const int* __restrict__ times,
    __hip_bfloat16* __restrict__ aout) {
  __shared__ __hip_bfloat16 Kl[128 * 64];   // [key row][64 d], chunk^=(row&7)
  __shared__ __hip_bfloat16 Vl[64 * 128];   // [d row][128 key], chunk^=(d&7)
  __shared__ __hip_bfloat16 Pl[4][16 * 128]; // per-wave P, byte^=(q&7)<<4
  const int tid = threadIdx.x, lane = tid & 63, wv = tid >> 6;
  const int r0 = lane & 15, kq = lane >> 4;
  int i = blockIdx.x;                 // 0..1087
  int xcd = i & 7, slot = i >> 3;     // slot 0..135
  int bhl = slot / 17;
  int qb = slot - bhl * 17;
  int bh = xcd * 8 + bhl;
  int b = bh >> 3, hh = bh & 7;
  char* plbase = (char*)&Pl[wv][0];

  const int qbase = qb * 64 + wv * 16;
  int qr = qbase + r0;
  if (qr > LL - 1) qr = LL - 1;
  const __hip_bfloat16* qp = qkv + (size_t)(b * LL + qr) * 1536 + hh * 64;
  bf16x8 qa0 = *(const bf16x8*)(qp + kq * 8);
  bf16x8 qa1 = *(const bf16x8*)(qp + 32 + kq * 8);
  int tq[4];
#pragma unroll
  for (int j = 0; j < 4; ++j) {
    int r = qbase + kq * 4 + j;
    tq[j] = (r < SS) ? times[b * SS + r] : TQ_CTX;
  }
  float m_run[4] = {-1e30f, -1e30f, -1e30f, -1e30f};
  float l_run[4] = {0.f, 0.f, 0.f, 0.f};
  f32x4 O[4] = {};
  const float scale = 0.125f;  // 1/sqrt(64)

  for (int kc = 0; kc < 9; ++kc) {
    __syncthreads();
#pragma unroll
    for (int c = 0; c < 4; ++c) {
      int chb = c * 256 + wv * 64;
      int ch = chb + lane;
      {
        int trow = ch >> 3, cp = ch & 7;
        int krow = kc * 128 + trow;
        if (krow > LL - 1) krow = LL - 1;
        int scp = cp ^ (trow & 7);
        gll16(qkv + (size_t)(b * LL + krow) * 1536 + 512 + hh * 64 + scp * 8,
              (char*)Kl + chb * 16);
      }
      {
        int d = ch >> 4, kp = ch & 15;
        int skp = kp ^ (d & 7);
        gll16(vt + ((size_t)(bh * 64 + d)) * KVPAD + kc * 128 + skp * 8,
              (char*)Vl + chb * 16);
      }
    }
    __syncthreads();
    f32x4 s[8] = {};
#pragma unroll
    for (int n = 0; n < 8; ++n) {
      int row = n * 16 + r0;
      bf16x8 kb0 = *(const bf16x8*)&Kl[row * 64 + ((kq ^ (row & 7)) * 8)];
      bf16x8 kb1 = *(const bf16x8*)&Kl[row * 64 + (((4 + kq) ^ (row & 7)) * 8)];
      s[n] = __builtin_amdgcn_mfma_f32_16x16x32_bf16(qa0, kb0, s[n], 0, 0, 0);
      s[n] = __builtin_amdgcn_mfma_f32_16x16x32_bf16(qa1, kb1, s[n], 0, 0, 0);
    }
    int tkn[8];
#pragma unroll
    for (int n = 0; n < 8; ++n) {
      int k = kc * 128 + 16 * n + r0;
      tkn[n] = (k < SS) ? times[b * SS + k] : ((k < LL) ? TK_CTX : TK_INV);
    }
    float mch[4] = {-1e30f, -1e30f, -1e30f, -1e30f};
#pragma unroll
    for (int n = 0; n < 8; ++n)
#pragma unroll
      for (int j = 0; j < 4; ++j) {
        float sv = (tq[j] >= tkn[n]) ? s[n][j] * scale : -1e30f;
        s[n][j] = sv;
        mch[j] = fmaxf(mch[j], sv);
      }
#pragma unroll
    for (int j = 0; j < 4; ++j) {
#pragma unroll
      for (int off = 1; off < 16; off <<= 1)
        mch[j] = fmaxf(mch[j], __shfl_xor(mch[j], off, 64));
    }
    float fac[4], psum[4];
#pragma unroll
    for (int j = 0; j < 4; ++j) {
      float mn = fmaxf(m_run[j], mch[j]);
      fac[j] = __expf(m_run[j] - mn);
      m_run[j] = mn;
      psum[j] = 0.f;
    }
#pragma unroll
    for (int n = 0; n < 8; ++n)
#pragma unroll
      for (int j = 0; j < 4; ++j) {
        float p = __expf(s[n][j] - m_run[j]);
        s[n][j] = p;
        psum[j] += p;
      }
#pragma unroll
    for (int j = 0; j < 4; ++j) {
#pragma unroll
      for (int off = 1; off < 16; off <<= 1)
        psum[j] += __shfl_xor(psum[j], off, 64);
      l_run[j] = l_run[j] * fac[j] + psum[j];
    }
#pragma unroll
    for (int n = 0; n < 4; ++n)
#pragma unroll
      for (int j = 0; j < 4; ++j) O[n][j] *= fac[j];
#pragma unroll
    for (int n = 0; n < 8; ++n)
#pragma unroll
      for (int j = 0; j < 4; ++j) {
        int q = kq * 4 + j;
        int byte = ((r0 + 16 * n) * 2) ^ ((q & 7) << 4);
        *(__hip_bfloat16*)(plbase + q * 256 + byte) = __float2bfloat16(s[n][j]);
      }
#pragma unroll
    for (int c = 0; c < 4; ++c) {
      int rbyte = (c * 64 + kq * 16) ^ ((r0 & 7) << 4);
      bf16x8 pa = *(const bf16x8*)(plbase + r0 * 256 + rbyte);
#pragma unroll
      for (int n = 0; n < 4; ++n) {
        int d = n * 16 + r0;
        int chv = (c * 4 + kq) ^ (r0 & 7);
        bf16x8 vb = *(const bf16x8*)&Vl[d * 128 + chv * 8];
        O[n] = __builtin_amdgcn_mfma_f32_16x16x32_bf16(pa, vb, O[n], 0, 0, 0);
      }
    }
  }
#pragma unroll
  for (int j = 0; j < 4; ++j) {
    int orow = qbase + kq * 4 + j;
    if (orow < LL) {
      float inv = 1.f / l_run[j];
#pragma unroll
      for (int n = 0; n < 4; ++n)
        aout[(size_t)(b * LL + orow) * DD + hh * 64 + n * 16 + r0] =
            __float2bfloat16(O[n][j] * inv);
    }
  }
}

// ---------------- residual + gemm-bias + layernorm (bf16 tmp) ----------------
// fout != nullptr: also write fp32 result to fout (final output, rows l<SS)
__global__ __launch_bounds__(256) void ln_fuse_k(float* __restrict__ x,
    const __hip_bfloat16* __restrict__ tmp, const float* __restrict__ gb,
    const float* __restrict__ w, const float* __restrict__ bias,
    __hip_bfloat16* __restrict__ xb, float* __restrict__ fout) {
  const int row = blockIdx.x;
  const int tid = threadIdx.x;
  size_t o = (size_t)row * DD + tid * 2;
  float2 v = *(const float2*)&x[o];
  const __hip_bfloat16* tp = tmp + o;
  float t0 = __bfloat162float(tp[0]);
  float t1 = __bfloat162float(tp[1]);
  float a0 = v.x + gb[tid * 2] + t0, a1 = v.y + gb[tid * 2 + 1] + t1;
  float s = a0 + a1, ss = a0 * a0 + a1 * a1;
#pragma unroll
  for (int off = 1; off < 64; off <<= 1) {
    s += __shfl_xor(s, off, 64);
    ss += __shfl_xor(ss, off, 64);
  }
  __shared__ float red[8];
  const int wv = tid >> 6, lane = tid & 63;
  if (lane == 0) { red[wv] = s; red[4 + wv] = ss; }
  __syncthreads();
  s = red[0] + red[1] + red[2] + red[3];
  ss = red[4] + red[5] + red[6] + red[7];
  float mean = s * (1.f / 512.f);
  float var = ss * (1.f / 512.f) - mean * mean;
  if (var < 0.f) var = 0.f;
  float rs = rsqrtf(var + 1e-5f);
  float w0 = w[tid * 2], w1 = w[tid * 2 + 1];
  float b0 = bias[tid * 2], b1 = bias[tid * 2 + 1];
  float y0 = (a0 - mean) * rs * w0 + b0;
  float y1 = (a1 - mean) * rs * w1 + b1;
  x[o] = y0; x[o + 1] = y1;
  xb[o] = __float2bfloat16(y0); xb[o + 1] = __float2bfloat16(y1);
  if (fout != nullptr) {
    int b = row / LL, l = row - b * LL;
    if (l < SS) {
      float* fp = fout + ((size_t)(b * SS + l)) * DD + tid * 2;
      fp[0] = y0; fp[1] = y1;
    }
  }
}

extern "C" void kernel_launch(void* const* d_in, const int* in_sizes, int n_in,
                              void* d_out, int out_size, void* d_ws, size_t ws_size,
                              hipStream_t stream) {
  (void)in_sizes; (void)n_in; (void)out_size; (void)ws_size;
  const float* src    = (const float*)d_in[0];
  const float* ctx    = (const float*)d_in[1];
  const int*   times  = (const int*)d_in[2];
  const int*   spaces = (const int*)d_in[3];
  const float* te     = (const float*)d_in[5];
  const float* se     = (const float*)d_in[6];
  const float* Wqkv   = (const float*)d_in[7];
  const float* bqkv   = (const float*)d_in[8];
  const float* Wo     = (const float*)d_in[9];
  const float* bo     = (const float*)d_in[10];
  const float* ln1w   = (const float*)d_in[11];
  const float* ln1b   = (const float*)d_in[12];
  const float* W1     = (const float*)d_in[13];
  const float* b1     = (const float*)d_in[14];
  const float* W2     = (const float*)d_in[15];
  const float* b2     = (const float*)d_in[16];
  const float* ln2w   = (const float*)d_in[17];
  const float* ln2b   = (const float*)d_in[18];

  char* ws = (char*)d_ws;
  size_t off = 0;
  auto alloc = [&](size_t bytes) {
    size_t o = off;
    off += (bytes + 255) & ~(size_t)255;
    return o;
  };
  float* x            = (float*)(ws + alloc((size_t)MP * DD * 4));
  __hip_bfloat16* xb  = (__hip_bfloat16*)(ws + alloc((size_t)MP * DD * 2));
  __hip_bfloat16* qkv = (__hip_bfloat16*)(ws + alloc((size_t)MP * 3 * DD * 2));
  __hip_bfloat16* abf = (__hip_bfloat16*)(ws + alloc((size_t)MP * DD * 2));
  __hip_bfloat16* hbf = (__hip_bfloat16*)(ws + alloc((size_t)MP * FF2 * 2));
  __hip_bfloat16* tmp = (__hip_bfloat16*)(ws + alloc((size_t)MP * DD * 2));
  __hip_bfloat16* vt  = (__hip_bfloat16*)(ws + alloc((size_t)BB * NH * HD * KVPAD * 2));
  __hip_bfloat16* wqb = (__hip_bfloat16*)(ws + alloc((size_t)NL * 3 * DD * DD * 2));
  __hip_bfloat16* wob = (__hip_bfloat16*)(ws + alloc((size_t)NL * DD * DD * 2));
  __hip_bfloat16* w1b = (__hip_bfloat16*)(ws + alloc((size_t)NL * FF2 * DD * 2));
  __hip_bfloat16* w2b = (__hip_bfloat16*)(ws + alloc((size_t)NL * DD * FF2 * 2));

  // weight conversion
  cvt_bf16_k<<<(NL * 3 * DD * DD) / 1024, 256, 0, stream>>>(Wqkv, wqb);
  cvt_bf16_k<<<(NL * DD * DD) / 1024, 256, 0, stream>>>(Wo, wob);
  cvt_bf16_k<<<(NL * FF2 * DD) / 1024, 256, 0, stream>>>(W1, w1b);
  cvt_bf16_k<<<(NL * DD * FF2) / 1024, 256, 0, stream>>>(W2, w2b);

  embed_k<<<MROWS, 256, 0, stream>>>(src, ctx, times, spaces, te, se, x, xb);

  for (int i = 0; i < NL; ++i) {
    gemm_bt2<1><<<65 * 6, 512, 0, stream>>>(
        xb, wqb + (size_t)i * 3 * DD * DD, bqkv + i * 3 * DD, qkv, DD, 3 * DD);
    vtrans_k<<<dim3(17, BB * NH), 256, 0, stream>>>(qkv, vt);
    attn_k<<<1088, 256, 0, stream>>>(qkv, vt, times, abf);
    gemm_bt<0><<<130 * 4, 256, 0, stream>>>(
        abf, wob + (size_t)i * DD * DD, nullptr, tmp, DD, DD);
    ln_fuse_k<<<MROWS, 256, 0, stream>>>(x, tmp, bo + i * DD,
                                         ln1w + i * DD, ln1b + i * DD, xb, nullptr);
    gemm_bt2<2><<<65 * 8, 512, 0, stream>>>(
        xb, w1b + (size_t)i * FF2 * DD, b1 + i * FF2, hbf, DD, FF2);
    gemm_bt<0><<<130 * 4, 256, 0, stream>>>(
        hbf, w2b + (size_t)i * DD * FF2, nullptr, tmp, FF2, DD);
    ln_fuse_k<<<MROWS, 256, 0, stream>>>(x, tmp, b2 + i * DD,
                                         ln2w + i * DD, ln2b + i * DD, xb,
                                         (i == NL - 1) ? (float*)d_out : nullptr);
  }
}